// Round 1
// baseline (561.060 us; speedup 1.0000x reference)
//
#include <hip/hip_runtime.h>
#include <math.h>

// Problem constants (fixed shapes)
//   BT=8, N=1024 (32x32), C=512, T=4 -> b=2, HEAD=8, c_h=64, ZONE=2
//   M = BT*N = 8192 rows for all projections
//   64 attention groups (b=2 * z^2=4 * head=8), each L=1024, d=64

// ---------------------------------------------------------------------------
// GEMM: C[M,N] = A[M,K] @ B[N,K]^T + bias[N]   (fp32 baseline)
// BM=BN=64, BK=16, 256 threads, 4x4 micro-tile per thread
// ---------------------------------------------------------------------------
__global__ __launch_bounds__(256)
void gemm_bt_bias(const float* __restrict__ A, const float* __restrict__ B,
                  const float* __restrict__ bias, float* __restrict__ C,
                  int M, int N, int K)
{
    __shared__ float As[16][68];  // [k][m], +4 pad keeps 16B alignment
    __shared__ float Bs[16][68];  // [k][n]
    const int tid = threadIdx.x;
    const int tx = tid & 15, ty = tid >> 4;
    const int m0 = blockIdx.y * 64, n0 = blockIdx.x * 64;
    const int lrow = tid >> 2, lc4 = tid & 3;

    float acc[4][4] = {};

    for (int k0 = 0; k0 < K; k0 += 16) {
        float4 a = *(const float4*)(A + (size_t)(m0 + lrow) * K + k0 + lc4 * 4);
        float4 b = *(const float4*)(B + (size_t)(n0 + lrow) * K + k0 + lc4 * 4);
        As[lc4*4+0][lrow] = a.x; As[lc4*4+1][lrow] = a.y;
        As[lc4*4+2][lrow] = a.z; As[lc4*4+3][lrow] = a.w;
        Bs[lc4*4+0][lrow] = b.x; Bs[lc4*4+1][lrow] = b.y;
        Bs[lc4*4+2][lrow] = b.z; Bs[lc4*4+3][lrow] = b.w;
        __syncthreads();
        #pragma unroll
        for (int k = 0; k < 16; ++k) {
            float av[4], bv[4];
            #pragma unroll
            for (int i = 0; i < 4; ++i) av[i] = As[k][ty*4+i];
            #pragma unroll
            for (int j = 0; j < 4; ++j) bv[j] = Bs[k][tx*4+j];
            #pragma unroll
            for (int i = 0; i < 4; ++i)
                #pragma unroll
                for (int j = 0; j < 4; ++j)
                    acc[i][j] = fmaf(av[i], bv[j], acc[i][j]);
        }
        __syncthreads();
    }

    #pragma unroll
    for (int i = 0; i < 4; ++i) {
        #pragma unroll
        for (int j = 0; j < 4; ++j) {
            int m = m0 + ty*4 + i, n = n0 + tx*4 + j;
            C[(size_t)m * N + n] = acc[i][j] + bias[n];
        }
    }
}

// ---------------------------------------------------------------------------
// Fused window attention (fp32, flash-style online softmax)
// grid: (16 q-tiles, 64 groups); block: 256 threads
// group g: b=g>>5, z=(g>>3)&3 (zi=z>>1, zj=z&1), h=g&7
// Window row l = t*256 + hi*16 + wj  maps to x-row (b*4+t)*1024+(zi*16+hi)*32+(zj*16+wj)
// ---------------------------------------------------------------------------
__global__ __launch_bounds__(256)
void window_attention(const float* __restrict__ q, const float* __restrict__ k,
                      const float* __restrict__ v, float* __restrict__ att)
{
    const int g  = blockIdx.y;
    const int b  = g >> 5, z = (g >> 3) & 3, h = g & 7;
    const int zi = z >> 1, zj = z & 1;
    const int qt = blockIdx.x;
    const int tid = threadIdx.x;
    const int tx = tid & 15, ty = tid >> 4;

    __shared__ float qs[64][68];  // [d][m]
    __shared__ float ks[64][68];  // [d][kk]
    __shared__ float vs[64][68];  // [kk][d]
    __shared__ float ps[64][68];  // [m][kk]

    const int colbase = h * 64;

    // ---- stage Q tile (transposed to [d][m]) ----
    #pragma unroll
    for (int i = 0; i < 4; ++i) {
        int idx = tid + 256 * i;
        int ll = idx >> 4, c4 = idx & 15;
        int l = qt * 64 + ll;
        int t = l >> 8, hi = (l >> 4) & 15, wj = l & 15;
        int row = ((b*4 + t) << 10) + ((zi*16 + hi) << 5) + (zj*16 + wj);
        float4 qv = *(const float4*)(q + (size_t)row * 512 + colbase + c4 * 4);
        qs[c4*4+0][ll] = qv.x; qs[c4*4+1][ll] = qv.y;
        qs[c4*4+2][ll] = qv.z; qs[c4*4+3][ll] = qv.w;
    }

    float o[4][4] = {};
    float m_run[4], l_run[4];
    #pragma unroll
    for (int i = 0; i < 4; ++i) { m_run[i] = -INFINITY; l_run[i] = 0.f; }

    for (int kt = 0; kt < 16; ++kt) {
        __syncthreads();  // protect ks/vs/ps from prior-iteration readers
        // ---- stage K (transposed) and V (natural) tiles ----
        #pragma unroll
        for (int i = 0; i < 4; ++i) {
            int idx = tid + 256 * i;
            int ll = idx >> 4, c4 = idx & 15;
            int l = kt * 64 + ll;
            int t = l >> 8, hi = (l >> 4) & 15, wj = l & 15;
            int row = ((b*4 + t) << 10) + ((zi*16 + hi) << 5) + (zj*16 + wj);
            size_t off = (size_t)row * 512 + colbase + c4 * 4;
            float4 kv = *(const float4*)(k + off);
            ks[c4*4+0][ll] = kv.x; ks[c4*4+1][ll] = kv.y;
            ks[c4*4+2][ll] = kv.z; ks[c4*4+3][ll] = kv.w;
            float4 vv = *(const float4*)(v + off);
            *(float4*)&vs[ll][c4*4] = vv;
        }
        __syncthreads();

        // ---- S = Q·K^T (4x4 per thread) ----
        float s[4][4] = {};
        #pragma unroll 8
        for (int d = 0; d < 64; ++d) {
            float av[4], bv[4];
            #pragma unroll
            for (int i = 0; i < 4; ++i) av[i] = qs[d][ty*4+i];
            #pragma unroll
            for (int j = 0; j < 4; ++j) bv[j] = ks[d][tx*4+j];
            #pragma unroll
            for (int i = 0; i < 4; ++i)
                #pragma unroll
                for (int j = 0; j < 4; ++j)
                    s[i][j] = fmaf(av[i], bv[j], s[i][j]);
        }

        // ---- online softmax update ----
        float scale_i[4];
        #pragma unroll
        for (int i = 0; i < 4; ++i) {
            float mx = fmaxf(fmaxf(s[i][0], s[i][1]), fmaxf(s[i][2], s[i][3]));
            mx *= 0.125f;
            mx = fmaxf(mx, __shfl_xor(mx, 1));
            mx = fmaxf(mx, __shfl_xor(mx, 2));
            mx = fmaxf(mx, __shfl_xor(mx, 4));
            mx = fmaxf(mx, __shfl_xor(mx, 8));
            float m_new = fmaxf(m_run[i], mx);
            scale_i[i] = __expf(m_run[i] - m_new);
            float rs = 0.f;
            #pragma unroll
            for (int j = 0; j < 4; ++j) {
                float p = __expf(s[i][j] * 0.125f - m_new);
                s[i][j] = p;          // reuse as P
                rs += p;
            }
            rs += __shfl_xor(rs, 1);
            rs += __shfl_xor(rs, 2);
            rs += __shfl_xor(rs, 4);
            rs += __shfl_xor(rs, 8);
            l_run[i] = l_run[i] * scale_i[i] + rs;
            m_run[i] = m_new;
        }

        // ---- write P tile, rescale O ----
        #pragma unroll
        for (int i = 0; i < 4; ++i) {
            #pragma unroll
            for (int j = 0; j < 4; ++j) {
                ps[ty*4+i][tx*4+j] = s[i][j];
                o[i][j] *= scale_i[i];
            }
        }
        __syncthreads();

        // ---- O += P @ V ----
        #pragma unroll 8
        for (int kk = 0; kk < 64; ++kk) {
            float pv[4], vv[4];
            #pragma unroll
            for (int i = 0; i < 4; ++i) pv[i] = ps[ty*4+i][kk];
            #pragma unroll
            for (int j = 0; j < 4; ++j) vv[j] = vs[kk][tx*4+j];
            #pragma unroll
            for (int i = 0; i < 4; ++i)
                #pragma unroll
                for (int j = 0; j < 4; ++j)
                    o[i][j] = fmaf(pv[i], vv[j], o[i][j]);
        }
    }

    // ---- normalize and scatter back to x-layout ----
    #pragma unroll
    for (int i = 0; i < 4; ++i) {
        int l = qt * 64 + ty*4 + i;
        int t = l >> 8, hi = (l >> 4) & 15, wj = l & 15;
        int row = ((b*4 + t) << 10) + ((zi*16 + hi) << 5) + (zj*16 + wj);
        float inv_l = 1.f / l_run[i];
        #pragma unroll
        for (int j = 0; j < 4; ++j)
            att[(size_t)row * 512 + colbase + tx*4 + j] = o[i][j] * inv_l;
    }
}

// ---------------------------------------------------------------------------
extern "C" void kernel_launch(void* const* d_in, const int* in_sizes, int n_in,
                              void* d_out, int out_size, void* d_ws, size_t ws_size,
                              hipStream_t stream) {
    const float* x  = (const float*)d_in[0];
    // d_in[1] = t (==4, hardcoded in shapes)
    const float* Wq = (const float*)d_in[2];
    const float* bq = (const float*)d_in[3];
    const float* Wk = (const float*)d_in[4];
    const float* bk = (const float*)d_in[5];
    const float* Wv = (const float*)d_in[6];
    const float* bv = (const float*)d_in[7];
    const float* Wo = (const float*)d_in[8];
    const float* bo = (const float*)d_in[9];
    float* out = (float*)d_out;

    const size_t MC = (size_t)8192 * 512;
    float* q   = (float*)d_ws;
    float* k   = q + MC;
    float* v   = k + MC;
    float* att = v + MC;

    dim3 gg(512 / 64, 8192 / 64);
    gemm_bt_bias<<<gg, 256, 0, stream>>>(x, Wq, bq, q, 8192, 512, 512);
    gemm_bt_bias<<<gg, 256, 0, stream>>>(x, Wk, bk, k, 8192, 512, 512);
    gemm_bt_bias<<<gg, 256, 0, stream>>>(x, Wv, bv, v, 8192, 512, 512);
    window_attention<<<dim3(16, 64), 256, 0, stream>>>(q, k, v, att);
    gemm_bt_bias<<<gg, 256, 0, stream>>>(att, Wo, bo, out, 8192, 512, 512);
}

// Round 2
// 133.455 us; speedup vs baseline: 4.2041x; 4.2041x over previous
//
#include <hip/hip_runtime.h>
#include <math.h>
#include <stdint.h>

// WindowMultiHeadedAttention — bf16 MFMA version
// Shapes: BT=8,N=1024,C=512,T=4 -> b=2, HEAD=8, c_h=64, ZONE=2
// M=8192 rows; 64 attention groups (b2*z4*h8), L=1024, d=64
//
// R2 design: convert x,W -> bf16; MFMA GEMMs (128x64x64 tiles, dbuf LDS via
// global_load_lds + XOR swizzle); flash attention with K via global_load_lds
// (swizzled), V reg-transposed to Vt (swizzled), P via padded LDS.

typedef unsigned short u16;
typedef __attribute__((ext_vector_type(8))) short bf16x8;
typedef __attribute__((ext_vector_type(4))) float f32x4;

__device__ __forceinline__ u16 f2b(float f) {
  uint32_t u = __float_as_uint(f);
  return (u16)((u + 0x7FFFu + ((u >> 16) & 1u)) >> 16);  // RNE
}

// global -> LDS direct copy, 16B per lane. LDS dest must be wave-uniform.
__device__ __forceinline__ void gld_lds16(const void* g, void* l) {
  auto gp = (__attribute__((address_space(1))) uint32_t*)(uintptr_t)g;
  auto lp = (__attribute__((address_space(3))) uint32_t*)(uint32_t)(uintptr_t)l;
  __builtin_amdgcn_global_load_lds(gp, lp, 16, 0, 0);
}

// ---------------------------------------------------------------------------
__global__ __launch_bounds__(256)
void cvt_f32_bf16(const float* __restrict__ src, u16* __restrict__ dst, int n4) {
  int i = blockIdx.x * 256 + threadIdx.x;
  if (i >= n4) return;
  float4 v = ((const float4*)src)[i];
  uint2 o;
  o.x = (uint32_t)f2b(v.x) | ((uint32_t)f2b(v.y) << 16);
  o.y = (uint32_t)f2b(v.z) | ((uint32_t)f2b(v.w) << 16);
  ((uint2*)dst)[i] = o;
}

// ---------------------------------------------------------------------------
// C[M,512] = A[M,512] @ B[512,512]^T + bias ; A,B bf16, out bf16 or f32.
// BM=128 BN=64 BK=64, 256 thr (4 waves, 2x2 wave grid of 64x32 tiles).
// ---------------------------------------------------------------------------
template<int OUTF32>
__global__ __launch_bounds__(256, 2)
void gemm_bf16(const u16* __restrict__ A, const u16* __restrict__ B,
               const float* __restrict__ bias, void* __restrict__ Cout)
{
  __shared__ u16 lds[2][12288];  // [A 128x64 | B 64x64] bf16, 24KB per buf
  const int tid = threadIdx.x;
  const int lane = tid & 63;
  const int wbase = (tid & 192) * 8;      // wave-uniform chunk base (u16 units)
  const int m0 = blockIdx.y * 128, n0 = blockIdx.x * 64;
  const int wm = ((tid >> 7) & 1) * 64;
  const int wn = ((tid >> 6) & 1) * 32;
  const int arow = tid >> 3;              // 0..31
  const int aslot = tid & 7;

  f32x4 acc[4][2];
  const f32x4 fz = {0.f, 0.f, 0.f, 0.f};
#pragma unroll
  for (int i = 0; i < 4; ++i)
#pragma unroll
    for (int j = 0; j < 2; ++j) acc[i][j] = fz;

  auto stage = [&](int t, int buf) {
#pragma unroll
    for (int q = 0; q < 4; ++q) {         // A tile: 128 rows x 64 k
      int row = q * 32 + arow;
      int sl = aslot ^ (row & 7);         // pre-swizzled source slot
      gld_lds16(A + (size_t)(m0 + row) * 512 + t * 64 + sl * 8,
                &lds[buf][q * 2048 + wbase]);
    }
#pragma unroll
    for (int q = 0; q < 2; ++q) {         // B tile: 64 rows x 64 k
      int row = q * 32 + arow;
      int sl = aslot ^ (row & 7);
      gld_lds16(B + (size_t)(n0 + row) * 512 + t * 64 + sl * 8,
                &lds[buf][8192 + q * 2048 + wbase]);
    }
  };

  stage(0, 0);
  __syncthreads();
  int cur = 0;
#pragma unroll 1
  for (int t = 0; t < 8; ++t) {
    if (t < 7) stage(t + 1, cur ^ 1);
    const u16* la = lds[cur];
    const u16* lb = lds[cur] + 8192;
    bf16x8 af[4][2];
#pragma unroll
    for (int mf = 0; mf < 4; ++mf)
#pragma unroll
      for (int ks = 0; ks < 2; ++ks) {
        int row = wm + mf * 16 + (lane & 15);
        int s = ks * 4 + (lane >> 4);
        af[mf][ks] = *(const bf16x8*)(la + row * 64 + ((s ^ (row & 7)) << 3));
      }
    __builtin_amdgcn_s_setprio(1);
#pragma unroll
    for (int ks = 0; ks < 2; ++ks)
#pragma unroll
      for (int nf = 0; nf < 2; ++nf) {
        int row = wn + nf * 16 + (lane & 15);
        int s = ks * 4 + (lane >> 4);
        bf16x8 bfr = *(const bf16x8*)(lb + row * 64 + ((s ^ (row & 7)) << 3));
#pragma unroll
        for (int mf = 0; mf < 4; ++mf)
          acc[mf][nf] = __builtin_amdgcn_mfma_f32_16x16x32_bf16(af[mf][ks], bfr, acc[mf][nf], 0, 0, 0);
      }
    __builtin_amdgcn_s_setprio(0);
    __syncthreads();
    cur ^= 1;
  }

#pragma unroll
  for (int mf = 0; mf < 4; ++mf)
#pragma unroll
    for (int nf = 0; nf < 2; ++nf) {
      int row = m0 + wm + mf * 16 + ((lane >> 4) << 2);
      int col = n0 + wn + nf * 16 + (lane & 15);
      float bi = bias[col];
#pragma unroll
      for (int r = 0; r < 4; ++r) {
        float vv = acc[mf][nf][r] + bi;
        if (OUTF32) ((float*)Cout)[(size_t)(row + r) * 512 + col] = vv;
        else        ((u16*)Cout)[(size_t)(row + r) * 512 + col] = f2b(vv);
      }
    }
}

// ---------------------------------------------------------------------------
// Flash attention, bf16 MFMA. grid (8 q-tiles, 64 groups), 256 thr.
// Wave owns 32 q rows. K in LDS (swizzled), V transposed to Vt (swizzled),
// P round-trips through padded LDS (stride 72).
// ---------------------------------------------------------------------------
__global__ __launch_bounds__(256)
void attn_bf16(const u16* __restrict__ qb, const u16* __restrict__ kb,
               const u16* __restrict__ vb, u16* __restrict__ attb)
{
  __shared__ u16 Kl[4096];       // [64 krow][64 d]  rows 128B, slot^=(row&7)
  __shared__ u16 Vt[4096];       // [64 d][64 m]     rows 128B, slot^=key(d)
  __shared__ u16 Pl[128 * 72];   // [128 qrow][72]   padded
  const int tid = threadIdx.x, lane = tid & 63, wid = tid >> 6;
  const int g = blockIdx.y, qt = blockIdx.x;
  const int b = g >> 5, z = (g >> 3) & 3, h = g & 7, zi = z >> 1, zj = z & 1;
  const int colbase = h * 64;
  const int rowbase = b * 4096 + zi * 512 + zj * 16;
  auto growrow = [&](int l) -> int {   // window row -> global row in [8192][512]
    return rowbase + ((l >> 8) << 10) + (((l >> 4) & 15) << 5) + (l & 15);
  };

  // Q fragments straight from global
  bf16x8 qf[2][2];
#pragma unroll
  for (int fi = 0; fi < 2; ++fi)
#pragma unroll
    for (int ks = 0; ks < 2; ++ks) {
      int ql = qt * 128 + wid * 32 + fi * 16 + (lane & 15);
      qf[fi][ks] = *(const bf16x8*)(qb + (size_t)growrow(ql) * 512 + colbase +
                                    ks * 32 + ((lane >> 4) << 3));
    }

  f32x4 o[2][4];
  const f32x4 fz = {0.f, 0.f, 0.f, 0.f};
#pragma unroll
  for (int fi = 0; fi < 2; ++fi)
#pragma unroll
    for (int dj = 0; dj < 4; ++dj) o[fi][dj] = fz;
  float mrun[2][4], lrun[2][4];
#pragma unroll
  for (int fi = 0; fi < 2; ++fi)
#pragma unroll
    for (int r = 0; r < 4; ++r) { mrun[fi][r] = -INFINITY; lrun[fi][r] = 0.f; }

#pragma unroll 1
  for (int c = 0; c < 16; ++c) {
    if (c) __syncthreads();   // prior chunk fully consumed before overwrite
    // --- stage K (direct to LDS, source pre-swizzled) ---
#pragma unroll
    for (int it = 0; it < 2; ++it) {
      int f = it * 256 + tid;
      int krow = f >> 3, slot = f & 7;
      gld_lds16(kb + (size_t)growrow(c * 64 + krow) * 512 + colbase +
                ((slot ^ (krow & 7)) << 3),
                Kl + it * 2048 + (tid & 192) * 8);
    }
    // --- load V, reg-transpose into Vt ---
    bf16x8 vr[2];
    int vm[2], vd0[2];
#pragma unroll
    for (int it = 0; it < 2; ++it) {
      int f = it * 256 + tid;
      vm[it] = f >> 3; vd0[it] = (f & 7) << 3;
      vr[it] = *(const bf16x8*)(vb + (size_t)growrow(c * 64 + vm[it]) * 512 +
                                colbase + vd0[it]);
    }
#pragma unroll
    for (int it = 0; it < 2; ++it)
#pragma unroll
      for (int e = 0; e < 8; ++e) {
        int d = vd0[it] + e;
        int key = (d & 7) ^ ((d >> 3) & 7);
        *(u16*)((char*)Vt + d * 128 + ((vm[it] * 2) ^ (key << 4))) = (u16)vr[it][e];
      }
    __syncthreads();

    // --- S = Q K^T ---
    f32x4 s[2][4];
#pragma unroll
    for (int fi = 0; fi < 2; ++fi)
#pragma unroll
      for (int fj = 0; fj < 4; ++fj) s[fi][fj] = fz;
    __builtin_amdgcn_s_setprio(1);
#pragma unroll
    for (int ks = 0; ks < 2; ++ks)
#pragma unroll
      for (int fj = 0; fj < 4; ++fj) {
        int j = fj * 16 + (lane & 15);
        int sl = ks * 4 + (lane >> 4);
        bf16x8 kf = *(const bf16x8*)(Kl + j * 64 + ((sl ^ (j & 7)) << 3));
        s[0][fj] = __builtin_amdgcn_mfma_f32_16x16x32_bf16(qf[0][ks], kf, s[0][fj], 0, 0, 0);
        s[1][fj] = __builtin_amdgcn_mfma_f32_16x16x32_bf16(qf[1][ks], kf, s[1][fj], 0, 0, 0);
      }
    __builtin_amdgcn_s_setprio(0);

    // --- online softmax (rows live in C-frag layout) ---
    const float sc = 0.125f;
#pragma unroll
    for (int fi = 0; fi < 2; ++fi)
#pragma unroll
      for (int r = 0; r < 4; ++r) {
        float mx = fmaxf(fmaxf(s[fi][0][r], s[fi][1][r]), fmaxf(s[fi][2][r], s[fi][3][r]));
        mx = fmaxf(mx, __shfl_xor(mx, 1));
        mx = fmaxf(mx, __shfl_xor(mx, 2));
        mx = fmaxf(mx, __shfl_xor(mx, 4));
        mx = fmaxf(mx, __shfl_xor(mx, 8));
        mx *= sc;
        float mn = fmaxf(mrun[fi][r], mx);
        float scl = __expf(mrun[fi][r] - mn);
        mrun[fi][r] = mn;
        float rs = 0.f;
        int prow = wid * 32 + fi * 16 + ((lane >> 4) << 2) + r;
#pragma unroll
        for (int fj = 0; fj < 4; ++fj) {
          float p = __expf(s[fi][fj][r] * sc - mn);
          rs += p;
          Pl[prow * 72 + fj * 16 + (lane & 15)] = f2b(p);
        }
        rs += __shfl_xor(rs, 1);
        rs += __shfl_xor(rs, 2);
        rs += __shfl_xor(rs, 4);
        rs += __shfl_xor(rs, 8);
        lrun[fi][r] = lrun[fi][r] * scl + rs;
#pragma unroll
        for (int dj = 0; dj < 4; ++dj) o[fi][dj][r] *= scl;
      }

    // --- O += P V  (P region is per-wave private; lgkm waits auto) ---
    __builtin_amdgcn_s_setprio(1);
#pragma unroll
    for (int ks = 0; ks < 2; ++ks) {
      bf16x8 pf0 = *(const bf16x8*)(Pl + (wid * 32 + (lane & 15)) * 72 +
                                    ks * 32 + ((lane >> 4) << 3));
      bf16x8 pf1 = *(const bf16x8*)(Pl + (wid * 32 + 16 + (lane & 15)) * 72 +
                                    ks * 32 + ((lane >> 4) << 3));
#pragma unroll
      for (int dj = 0; dj < 4; ++dj) {
        int d = dj * 16 + (lane & 15);
        int key = (d & 7) ^ ((d >> 3) & 7);
        bf16x8 vf = *(const bf16x8*)((const char*)Vt + d * 128 +
                                     ((ks * 64 + ((lane >> 4) << 4)) ^ (key << 4)));
        o[0][dj] = __builtin_amdgcn_mfma_f32_16x16x32_bf16(pf0, vf, o[0][dj], 0, 0, 0);
        o[1][dj] = __builtin_amdgcn_mfma_f32_16x16x32_bf16(pf1, vf, o[1][dj], 0, 0, 0);
      }
    }
    __builtin_amdgcn_s_setprio(0);
  }

  // --- epilogue: normalize, store bf16 in x-layout ---
#pragma unroll
  for (int fi = 0; fi < 2; ++fi)
#pragma unroll
    for (int r = 0; r < 4; ++r) {
      int ql = qt * 128 + wid * 32 + fi * 16 + ((lane >> 4) << 2) + r;
      size_t rowoff = (size_t)growrow(ql) * 512 + colbase;
      float inv = 1.f / lrun[fi][r];
#pragma unroll
      for (int dj = 0; dj < 4; ++dj)
        attb[rowoff + dj * 16 + (lane & 15)] = f2b(o[fi][dj][r] * inv);
    }
}

// ---------------------------------------------------------------------------
extern "C" void kernel_launch(void* const* d_in, const int* in_sizes, int n_in,
                              void* d_out, int out_size, void* d_ws, size_t ws_size,
                              hipStream_t stream) {
  const float* x  = (const float*)d_in[0];
  const float* Wq = (const float*)d_in[2];
  const float* bq = (const float*)d_in[3];
  const float* Wk = (const float*)d_in[4];
  const float* bk = (const float*)d_in[5];
  const float* Wv = (const float*)d_in[6];
  const float* bv = (const float*)d_in[7];
  const float* Wo = (const float*)d_in[8];
  const float* bo = (const float*)d_in[9];

  u16* xb   = (u16*)d_ws;            // 8192*512
  u16* wqb  = xb + 4194304;          // 512*512 each
  u16* wkb  = wqb + 262144;
  u16* wvb  = wkb + 262144;
  u16* wob  = wvb + 262144;
  u16* qbuf = wob + 262144;          // 8192*512 each
  u16* kbuf = qbuf + 4194304;
  u16* vbuf = kbuf + 4194304;
  u16* attb = vbuf + 4194304;

  cvt_f32_bf16<<<4096, 256, 0, stream>>>(x, xb, 1048576);
  cvt_f32_bf16<<<256, 256, 0, stream>>>(Wq, wqb, 65536);
  cvt_f32_bf16<<<256, 256, 0, stream>>>(Wk, wkb, 65536);
  cvt_f32_bf16<<<256, 256, 0, stream>>>(Wv, wvb, 65536);
  cvt_f32_bf16<<<256, 256, 0, stream>>>(Wo, wob, 65536);

  dim3 gg(8, 64);
  gemm_bf16<0><<<gg, 256, 0, stream>>>(xb, wqb, bq, qbuf);
  gemm_bf16<0><<<gg, 256, 0, stream>>>(xb, wkb, bk, kbuf);
  gemm_bf16<0><<<gg, 256, 0, stream>>>(xb, wvb, bv, vbuf);
  attn_bf16<<<dim3(8, 64), 256, 0, stream>>>(qbuf, kbuf, vbuf, attb);
  gemm_bf16<1><<<gg, 256, 0, stream>>>(attb, wob, bo, d_out);
}

// Round 3
// 115.511 us; speedup vs baseline: 4.8572x; 1.1553x over previous
//
#include <hip/hip_runtime.h>
#include <math.h>
#include <stdint.h>

// WindowMultiHeadedAttention R3 — 32x32 swapped-QK^T MFMA attention, no-LDS attn,
// fused QKV GEMM with layout-transforming epilogues.
// Shapes: BT=8,N=1024,C=512,T=4 -> b=2, HEAD=8, c_h=64, ZONE=2
// 64 groups (b2*z4*h8), L=1024, d=64.
// Layouts in workspace:
//   qw,kw: [64 g][1024 l][64 d] bf16   (window-gathered)
//   vt:    [64 g][64 d][1024 l] bf16   (window-gathered, transposed)
//   attb:  x-layout [8192][512] bf16

typedef unsigned short u16;
typedef unsigned int u32;
typedef __attribute__((ext_vector_type(8))) short bf16x8;
typedef __attribute__((ext_vector_type(4))) float f32x4;
typedef __attribute__((ext_vector_type(16))) float f32x16;

__device__ __forceinline__ u16 f2b(float f) {
  u32 u = __float_as_uint(f);
  return (u16)((u + 0x7FFFu + ((u >> 16) & 1u)) >> 16);  // RNE
}

__device__ __forceinline__ void gld_lds16(const void* g, void* l) {
  auto gp = (__attribute__((address_space(1))) u32*)(uintptr_t)g;
  auto lp = (__attribute__((address_space(3))) u32*)(u32)(uintptr_t)l;
  __builtin_amdgcn_global_load_lds(gp, lp, 16, 0, 0);
}

// ---------------------------------------------------------------------------
// prep: convert x and 4 weights fp32 -> bf16 in one launch (float4 granules)
// ---------------------------------------------------------------------------
__global__ __launch_bounds__(256)
void prep_cvt(const float* __restrict__ x, const float* __restrict__ wq,
              const float* __restrict__ wk, const float* __restrict__ wv,
              const float* __restrict__ wo, u16* __restrict__ xb,
              u16* __restrict__ wqb, u16* __restrict__ wkb,
              u16* __restrict__ wvb, u16* __restrict__ wob)
{
  int i = blockIdx.x * 256 + threadIdx.x;
  const float* src; u16* dst; int off;
  if (i < 1048576) { src = x; dst = xb; off = i; }
  else {
    int j = i - 1048576; int w = j >> 16; off = j & 65535;
    src = (w == 0) ? wq : (w == 1) ? wk : (w == 2) ? wv : wo;
    dst = (w == 0) ? wqb : (w == 1) ? wkb : (w == 2) ? wvb : wob;
  }
  float4 v = ((const float4*)src)[off];
  ushort4 o;
  o.x = f2b(v.x); o.y = f2b(v.y); o.z = f2b(v.z); o.w = f2b(v.w);
  ((ushort4*)dst)[off] = o;
}

// ---------------------------------------------------------------------------
// Fused QKV GEMM: q/k/v[m][n] = x[m][:] . W{q,k,v}[n][:] + b
// BM=128 BN=64 BK=64, 256 thr. Epilogue: q,k -> [g][l][d]; v -> [g][d][l].
// ---------------------------------------------------------------------------
__global__ __launch_bounds__(256, 2)
void gemm_qkv(const u16* __restrict__ A, const u16* __restrict__ Bq,
              const u16* __restrict__ Bk, const u16* __restrict__ Bv,
              const float* __restrict__ bq, const float* __restrict__ bk,
              const float* __restrict__ bv, u16* __restrict__ qw,
              u16* __restrict__ kw, u16* __restrict__ vt)
{
  __shared__ u16 As[2][8192];      // 128x64
  __shared__ u16 Ws[3][2][4096];   // 3 x 64x64
  const int tid = threadIdx.x;
  const int lane = tid & 63;
  const int wbase = (tid & 192) * 8;
  const int m0 = blockIdx.y * 128, n0 = blockIdx.x * 64;
  const int wm = ((tid >> 7) & 1) * 64;
  const int wn = ((tid >> 6) & 1) * 32;
  const int arow = tid >> 3, aslot = tid & 7;

  f32x4 accq[4][2], acck[4][2], accv[4][2];
#pragma unroll
  for (int i = 0; i < 4; ++i)
#pragma unroll
    for (int j = 0; j < 2; ++j) {
#pragma unroll
      for (int r = 0; r < 4; ++r) { accq[i][j][r] = 0.f; acck[i][j][r] = 0.f; accv[i][j][r] = 0.f; }
    }

  auto stage = [&](int t, int buf) {
#pragma unroll
    for (int q = 0; q < 4; ++q) {
      int row = q * 32 + arow;
      int sl = aslot ^ (row & 7);
      gld_lds16(A + (size_t)(m0 + row) * 512 + t * 64 + sl * 8,
                &As[buf][q * 2048 + wbase]);
    }
    const u16* bp[3] = {Bq, Bk, Bv};
#pragma unroll
    for (int w = 0; w < 3; ++w)
#pragma unroll
      for (int q = 0; q < 2; ++q) {
        int row = q * 32 + arow;
        int sl = aslot ^ (row & 7);
        gld_lds16(bp[w] + (size_t)(n0 + row) * 512 + t * 64 + sl * 8,
                  &Ws[w][buf][q * 2048 + wbase]);
      }
  };

  stage(0, 0);
  __syncthreads();
  int cur = 0;
#pragma unroll 1
  for (int t = 0; t < 8; ++t) {
    if (t < 7) stage(t + 1, cur ^ 1);
    const u16* la = As[cur];
    bf16x8 af[4][2];
#pragma unroll
    for (int mf = 0; mf < 4; ++mf)
#pragma unroll
      for (int ks = 0; ks < 2; ++ks) {
        int row = wm + mf * 16 + (lane & 15);
        int s = ks * 4 + (lane >> 4);
        af[mf][ks] = *(const bf16x8*)(la + row * 64 + ((s ^ (row & 7)) << 3));
      }
    __builtin_amdgcn_s_setprio(1);
#pragma unroll
    for (int ks = 0; ks < 2; ++ks)
#pragma unroll
      for (int nf = 0; nf < 2; ++nf) {
        int row = wn + nf * 16 + (lane & 15);
        int s = ks * 4 + (lane >> 4);
        int boff = row * 64 + ((s ^ (row & 7)) << 3);
        bf16x8 bq8 = *(const bf16x8*)(Ws[0][cur] + boff);
        bf16x8 bk8 = *(const bf16x8*)(Ws[1][cur] + boff);
        bf16x8 bv8 = *(const bf16x8*)(Ws[2][cur] + boff);
#pragma unroll
        for (int mf = 0; mf < 4; ++mf) {
          accq[mf][nf] = __builtin_amdgcn_mfma_f32_16x16x32_bf16(af[mf][ks], bq8, accq[mf][nf], 0, 0, 0);
          acck[mf][nf] = __builtin_amdgcn_mfma_f32_16x16x32_bf16(af[mf][ks], bk8, acck[mf][nf], 0, 0, 0);
          accv[mf][nf] = __builtin_amdgcn_mfma_f32_16x16x32_bf16(af[mf][ks], bv8, accv[mf][nf], 0, 0, 0);
        }
      }
    __builtin_amdgcn_s_setprio(0);
    __syncthreads();
    cur ^= 1;
  }

  // epilogue
  int h[2], d[2]; float bqv[2], bkv[2], bvv[2];
#pragma unroll
  for (int nf = 0; nf < 2; ++nf) {
    int col = n0 + wn + nf * 16 + (lane & 15);
    h[nf] = col >> 6; d[nf] = col & 63;
    bqv[nf] = bq[col]; bkv[nf] = bk[col]; bvv[nf] = bv[col];
  }
#pragma unroll
  for (int mf = 0; mf < 4; ++mf) {
    int mb = m0 + wm + mf * 16 + ((lane >> 4) << 2);
    int b = mb >> 12, t = (mb >> 10) & 3, row32 = (mb >> 5) & 31, col32 = mb & 31;
    int zi = row32 >> 4, hirow = row32 & 15, zj = col32 >> 4, wj = col32 & 15;
    int gb = b * 32 + (zi * 2 + zj) * 8;
    int l0 = t * 256 + hirow * 16 + wj;
#pragma unroll
    for (int nf = 0; nf < 2; ++nf) {
      size_t qkbase = ((size_t)(gb + h[nf]) * 1024 + l0) * 64 + d[nf];
#pragma unroll
      for (int r = 0; r < 4; ++r) {
        qw[qkbase + (size_t)r * 64] = f2b(accq[mf][nf][r] + bqv[nf]);
        kw[qkbase + (size_t)r * 64] = f2b(acck[mf][nf][r] + bkv[nf]);
      }
      ushort4 pv;
      pv.x = f2b(accv[mf][nf][0] + bvv[nf]);
      pv.y = f2b(accv[mf][nf][1] + bvv[nf]);
      pv.z = f2b(accv[mf][nf][2] + bvv[nf]);
      pv.w = f2b(accv[mf][nf][3] + bvv[nf]);
      *(ushort4*)(vt + ((size_t)(gb + h[nf]) * 64 + d[nf]) * 1024 + l0) = pv;
    }
  }
}

// ---------------------------------------------------------------------------
// Attention: 32x32 MFMA, swapped QK^T, in-register softmax, no LDS.
// grid (8 q-tiles, 64 groups), 256 thr (4 indep waves, 32 q-rows each).
// ---------------------------------------------------------------------------
__global__ __launch_bounds__(256)
void attn32(const u16* __restrict__ qw, const u16* __restrict__ kw,
            const u16* __restrict__ vt, u16* __restrict__ attb)
{
  const int tid = threadIdx.x, lane = tid & 63, wid = tid >> 6;
  const int hi = lane >> 5, ln = lane & 31;
  const int g = blockIdx.y, qt = blockIdx.x;
  const int b = g >> 5, z = (g >> 3) & 3, h = g & 7, zi = z >> 1, zj = z & 1;
  const u16* qg = qw + (size_t)g * 65536;
  const u16* kg = kw + (size_t)g * 65536;
  const u16* vg = vt + (size_t)g * 65536;
  const int q0 = qt * 128 + wid * 32;
  const float SC2 = 0.125f * 1.44269504089f;   // scale * log2(e)
  const float THR2 = 11.5415603f;              // 8 * log2(e)

  bf16x8 qf[4];
#pragma unroll
  for (int ks = 0; ks < 4; ++ks)
    qf[ks] = *(const bf16x8*)(qg + (size_t)(q0 + ln) * 64 + ks * 16 + hi * 8);

  f32x16 o[2];
#pragma unroll
  for (int nf = 0; nf < 2; ++nf)
#pragma unroll
    for (int r = 0; r < 16; ++r) o[nf][r] = 0.f;
  float m2run = -INFINITY, lrun = 0.f;

  bf16x8 kA[2][4], vA[4][2], kB[2][4], vB[4][2];

  auto loadK = [&](int c, bf16x8 (&kk)[2][4]) {
    const u16* base = kg + (size_t)(c * 64 + ln) * 64 + hi * 8;
#pragma unroll
    for (int kb = 0; kb < 2; ++kb)
#pragma unroll
      for (int ks = 0; ks < 4; ++ks)
        kk[kb][ks] = *(const bf16x8*)(base + kb * 32 * 64 + ks * 16);
  };
  auto loadV = [&](int c, bf16x8 (&vv)[4][2]) {
    const u16* base = vg + (size_t)ln * 1024 + c * 64 + hi * 8;
#pragma unroll
    for (int ks = 0; ks < 4; ++ks)
#pragma unroll
      for (int nf = 0; nf < 2; ++nf)
        vv[ks][nf] = *(const bf16x8*)(base + (size_t)nf * 32 * 1024 + ks * 16);
  };

  auto body = [&](int c, bf16x8 (&kc)[2][4], bf16x8 (&vc)[4][2],
                  bf16x8 (&kn)[2][4], bf16x8 (&vn)[4][2]) {
    if (c < 15) { loadK(c + 1, kn); loadV(c + 1, vn); }
    // S^T = K . Q^T  (32x32 frags; rows=keys, cols=q)
    f32x16 st[2];
#pragma unroll
    for (int kb = 0; kb < 2; ++kb)
#pragma unroll
      for (int r = 0; r < 16; ++r) st[kb][r] = 0.f;
    __builtin_amdgcn_s_setprio(1);
#pragma unroll
    for (int ks = 0; ks < 4; ++ks) {
      st[0] = __builtin_amdgcn_mfma_f32_32x32x16_bf16(kA[0][0], qf[ks], st[0], 0, 0, 0);
      st[1] = __builtin_amdgcn_mfma_f32_32x32x16_bf16(kc[1][ks], qf[ks], st[1], 0, 0, 0);
      // note: first operand above for st[0] must be kc[0][ks]; fixed below
      (void)0;
    }
    __builtin_amdgcn_s_setprio(0);
    // (placeholder removed in real code path below)
    (void)kc;
  };
  (void)body; // the lambda above is not used; explicit loop below

  loadK(0, kA); loadV(0, vA);

#pragma unroll 1
  for (int cc = 0; cc < 16; cc += 2) {
#pragma unroll
    for (int half = 0; half < 2; ++half) {
      const int c = cc + half;
      bf16x8 (&kc)[2][4] = half ? kB : kA;
      bf16x8 (&vc)[4][2] = half ? vB : vA;
      bf16x8 (&kn)[2][4] = half ? kA : kB;
      bf16x8 (&vn)[4][2] = half ? vA : vB;
      if (c < 15) { loadK(c + 1, kn); loadV(c + 1, vn); }

      // ---- S^T = K Q^T ----
      f32x16 st[2];
#pragma unroll
      for (int kb = 0; kb < 2; ++kb)
#pragma unroll
        for (int r = 0; r < 16; ++r) st[kb][r] = 0.f;
      __builtin_amdgcn_s_setprio(1);
#pragma unroll
      for (int ks = 0; ks < 4; ++ks) {
        st[0] = __builtin_amdgcn_mfma_f32_32x32x16_bf16(kc[0][ks], qf[ks], st[0], 0, 0, 0);
        st[1] = __builtin_amdgcn_mfma_f32_32x32x16_bf16(kc[1][ks], qf[ks], st[1], 0, 0, 0);
      }
      __builtin_amdgcn_s_setprio(0);

      // ---- online softmax (lane owns q=ln; 32 key-values in regs) ----
      float mx = st[0][0];
#pragma unroll
      for (int r = 1; r < 16; ++r) mx = fmaxf(mx, st[0][r]);
#pragma unroll
      for (int r = 0; r < 16; ++r) mx = fmaxf(mx, st[1][r]);
      mx = fmaxf(mx, __shfl_xor(mx, 32));
      float mx2 = mx * SC2;
      if (!__all(mx2 <= m2run + THR2)) {
        float mn = fmaxf(m2run, mx2);
        float scl = exp2f(m2run - mn);
        lrun *= scl;
        m2run = mn;
#pragma unroll
        for (int r = 0; r < 16; ++r) {
          float sb = __shfl(scl, (r & 3) + 8 * (r >> 2) + 4 * hi);
          o[0][r] *= sb; o[1][r] *= sb;
        }
      }
      float nm = -m2run;
      float rs = 0.f;
#pragma unroll
      for (int kb = 0; kb < 2; ++kb)
#pragma unroll
        for (int r = 0; r < 16; ++r) {
          float p = exp2f(fmaf(st[kb][r], SC2, nm));
          st[kb][r] = p;
          rs += p;
        }
      rs += __shfl_xor(rs, 32);
      lrun += rs;

      // ---- P (C-layout) -> A-frag via cvt_pk + permlane32_swap ----
      u32 W[2][4][2];
#pragma unroll
      for (int kb = 0; kb < 2; ++kb)
#pragma unroll
        for (int j = 0; j < 4; ++j)
#pragma unroll
          for (int u = 0; u < 2; ++u) {
            u32 w;
            asm("v_cvt_pk_bf16_f32 %0, %1, %2"
                : "=v"(w) : "v"(st[kb][4 * j + 2 * u]), "v"(st[kb][4 * j + 2 * u + 1]));
            W[kb][j][u] = w;
          }
      __builtin_amdgcn_s_setprio(1);
#pragma unroll
      for (int ks = 0; ks < 4; ++ks) {
        const int kb = ks >> 1, sl = ks & 1;
        u32 a0 = W[kb][2 * sl][0], b0 = W[kb][2 * sl + 1][0];
        u32 a1 = W[kb][2 * sl][1], b1 = W[kb][2 * sl + 1][1];
        asm volatile("v_permlane32_swap_b32 %0, %1" : "+v"(a0), "+v"(b0));
        asm volatile("v_permlane32_swap_b32 %0, %1" : "+v"(a1), "+v"(b1));
        union { u32 u[4]; bf16x8 v; } pu;
        pu.u[0] = a0; pu.u[1] = a1; pu.u[2] = b0; pu.u[3] = b1;
        o[0] = __builtin_amdgcn_mfma_f32_32x32x16_bf16(pu.v, vc[ks][0], o[0], 0, 0, 0);
        o[1] = __builtin_amdgcn_mfma_f32_32x32x16_bf16(pu.v, vc[ks][1], o[1], 0, 0, 0);
      }
      __builtin_amdgcn_s_setprio(0);
    }
  }

  // ---- epilogue: normalize, store bf16 to x-layout ----
  const int rowbase = b * 4096 + zi * 512 + zj * 16;
  const int colbase = h * 64;
#pragma unroll
  for (int r = 0; r < 16; ++r) {
    int qr = (r & 3) + 8 * (r >> 2) + 4 * hi;
    float lv = __shfl(lrun, qr);
    float iv = 1.f / lv;
    int l = q0 + qr;
    int row = rowbase + ((l >> 8) << 10) + (((l >> 4) & 15) << 5) + (l & 15);
    size_t off = (size_t)row * 512 + colbase + ln;
    attb[off] = f2b(o[0][r] * iv);
    attb[off + 32] = f2b(o[1][r] * iv);
  }
}

// ---------------------------------------------------------------------------
// Output GEMM (from R2): out[m][n] = att[m][:] . Wo[n][:] + bo, f32 out
// ---------------------------------------------------------------------------
__global__ __launch_bounds__(256, 2)
void gemm_o(const u16* __restrict__ A, const u16* __restrict__ B,
            const float* __restrict__ bias, float* __restrict__ Cout)
{
  __shared__ u16 lds[2][12288];
  const int tid = threadIdx.x;
  const int lane = tid & 63;
  const int wbase = (tid & 192) * 8;
  const int m0 = blockIdx.y * 128, n0 = blockIdx.x * 64;
  const int wm = ((tid >> 7) & 1) * 64;
  const int wn = ((tid >> 6) & 1) * 32;
  const int arow = tid >> 3, aslot = tid & 7;

  f32x4 acc[4][2];
#pragma unroll
  for (int i = 0; i < 4; ++i)
#pragma unroll
    for (int j = 0; j < 2; ++j)
#pragma unroll
      for (int r = 0; r < 4; ++r) acc[i][j][r] = 0.f;

  auto stage = [&](int t, int buf) {
#pragma unroll
    for (int q = 0; q < 4; ++q) {
      int row = q * 32 + arow;
      int sl = aslot ^ (row & 7);
      gld_lds16(A + (size_t)(m0 + row) * 512 + t * 64 + sl * 8,
                &lds[buf][q * 2048 + wbase]);
    }
#pragma unroll
    for (int q = 0; q < 2; ++q) {
      int row = q * 32 + arow;
      int sl = aslot ^ (row & 7);
      gld_lds16(B + (size_t)(n0 + row) * 512 + t * 64 + sl * 8,
                &lds[buf][8192 + q * 2048 + wbase]);
    }
  };

  stage(0, 0);
  __syncthreads();
  int cur = 0;
#pragma unroll 1
  for (int t = 0; t < 8; ++t) {
    if (t < 7) stage(t + 1, cur ^ 1);
    const u16* la = lds[cur];
    const u16* lb = lds[cur] + 8192;
    bf16x8 af[4][2];
#pragma unroll
    for (int mf = 0; mf < 4; ++mf)
#pragma unroll
      for (int ks = 0; ks < 2; ++ks) {
        int row = wm + mf * 16 + (lane & 15);
        int s = ks * 4 + (lane >> 4);
        af[mf][ks] = *(const bf16x8*)(la + row * 64 + ((s ^ (row & 7)) << 3));
      }
    __builtin_amdgcn_s_setprio(1);
#pragma unroll
    for (int ks = 0; ks < 2; ++ks)
#pragma unroll
      for (int nf = 0; nf < 2; ++nf) {
        int row = wn + nf * 16 + (lane & 15);
        int s = ks * 4 + (lane >> 4);
        bf16x8 bfr = *(const bf16x8*)(lb + row * 64 + ((s ^ (row & 7)) << 3));
#pragma unroll
        for (int mf = 0; mf < 4; ++mf)
          acc[mf][nf] = __builtin_amdgcn_mfma_f32_16x16x32_bf16(af[mf][ks], bfr, acc[mf][nf], 0, 0, 0);
      }
    __builtin_amdgcn_s_setprio(0);
    __syncthreads();
    cur ^= 1;
  }

#pragma unroll
  for (int mf = 0; mf < 4; ++mf)
#pragma unroll
    for (int nf = 0; nf < 2; ++nf) {
      int row = m0 + wm + mf * 16 + ((lane >> 4) << 2);
      int col = n0 + wn + nf * 16 + (lane & 15);
      float bi = bias[col];
#pragma unroll
      for (int r = 0; r < 4; ++r)
        Cout[(size_t)(row + r) * 512 + col] = acc[mf][nf][r] + bi;
    }
}

// ---------------------------------------------------------------------------
extern "C" void kernel_launch(void* const* d_in, const int* in_sizes, int n_in,
                              void* d_out, int out_size, void* d_ws, size_t ws_size,
                              hipStream_t stream) {
  const float* x  = (const float*)d_in[0];
  const float* Wq = (const float*)d_in[2];
  const float* bq = (const float*)d_in[3];
  const float* Wk = (const float*)d_in[4];
  const float* bk = (const float*)d_in[5];
  const float* Wv = (const float*)d_in[6];
  const float* bv = (const float*)d_in[7];
  const float* Wo = (const float*)d_in[8];
  const float* bo = (const float*)d_in[9];

  u16* xb   = (u16*)d_ws;            // 8192*512
  u16* wqb  = xb + 4194304;
  u16* wkb  = wqb + 262144;
  u16* wvb  = wkb + 262144;
  u16* wob  = wvb + 262144;
  u16* qwb  = wob + 262144;          // [64][1024][64]
  u16* kwb  = qwb + 4194304;
  u16* vtb  = kwb + 4194304;         // [64][64][1024]
  u16* attb = vtb + 4194304;         // x-layout

  prep_cvt<<<5120, 256, 0, stream>>>(x, Wq, Wk, Wv, Wo, xb, wqb, wkb, wvb, wob);
  gemm_qkv<<<dim3(8, 64), 256, 0, stream>>>(xb, wqb, wkb, wvb, bq, bk, bv, qwb, kwb, vtb);
  attn32<<<dim3(8, 64), 256, 0, stream>>>(qwb, kwb, vtb, attb);
  gemm_o<<<dim3(8, 64), 256, 0, stream>>>(attb, wob, bo, (float*)d_out);
}

// Round 4
// 91.060 us; speedup vs baseline: 6.1614x; 1.2685x over previous
//
#include <hip/hip_runtime.h>
#include <math.h>
#include <stdint.h>

// WindowMultiHeadedAttention R4 — attn: swapped-QK^T 32x32 MFMA, LDS-staged
// K/V^T via global_load_lds (double-buffered), XCD-swizzled grid.
// Layouts in workspace:
//   qw,kw: [64 g][1024 l][64 d] bf16   (window-gathered)
//   vt:    [64 g][64 d][1024 l] bf16   (window-gathered, transposed)
//   attb:  x-layout [8192][512] bf16

typedef unsigned short u16;
typedef unsigned int u32;
typedef __attribute__((ext_vector_type(8))) short bf16x8;
typedef __attribute__((ext_vector_type(4))) float f32x4;
typedef __attribute__((ext_vector_type(16))) float f32x16;

__device__ __forceinline__ u16 f2b(float f) {
  u32 u = __float_as_uint(f);
  return (u16)((u + 0x7FFFu + ((u >> 16) & 1u)) >> 16);  // RNE
}

__device__ __forceinline__ void gld_lds16(const void* g, void* l) {
  auto gp = (__attribute__((address_space(1))) u32*)(uintptr_t)g;
  auto lp = (__attribute__((address_space(3))) u32*)(u32)(uintptr_t)l;
  __builtin_amdgcn_global_load_lds(gp, lp, 16, 0, 0);
}

// ---------------------------------------------------------------------------
// prep: convert x and 4 weights fp32 -> bf16 in one launch (float4 granules)
// ---------------------------------------------------------------------------
__global__ __launch_bounds__(256)
void prep_cvt(const float* __restrict__ x, const float* __restrict__ wq,
              const float* __restrict__ wk, const float* __restrict__ wv,
              const float* __restrict__ wo, u16* __restrict__ xb,
              u16* __restrict__ wqb, u16* __restrict__ wkb,
              u16* __restrict__ wvb, u16* __restrict__ wob)
{
  int i = blockIdx.x * 256 + threadIdx.x;
  const float* src; u16* dst; int off;
  if (i < 1048576) { src = x; dst = xb; off = i; }
  else {
    int j = i - 1048576; int w = j >> 16; off = j & 65535;
    src = (w == 0) ? wq : (w == 1) ? wk : (w == 2) ? wv : wo;
    dst = (w == 0) ? wqb : (w == 1) ? wkb : (w == 2) ? wvb : wob;
  }
  float4 v = ((const float4*)src)[off];
  ushort4 o;
  o.x = f2b(v.x); o.y = f2b(v.y); o.z = f2b(v.z); o.w = f2b(v.w);
  ((ushort4*)dst)[off] = o;
}

// ---------------------------------------------------------------------------
// Fused QKV GEMM: q/k/v[m][n] = x[m][:] . W{q,k,v}[n][:] + b
// BM=128 BN=64 BK=64, 256 thr. Epilogue: q,k -> [g][l][d]; v -> [g][d][l].
// ---------------------------------------------------------------------------
__global__ __launch_bounds__(256, 2)
void gemm_qkv(const u16* __restrict__ A, const u16* __restrict__ Bq,
              const u16* __restrict__ Bk, const u16* __restrict__ Bv,
              const float* __restrict__ bq, const float* __restrict__ bk,
              const float* __restrict__ bv, u16* __restrict__ qw,
              u16* __restrict__ kw, u16* __restrict__ vt)
{
  __shared__ u16 As[2][8192];      // 128x64
  __shared__ u16 Ws[3][2][4096];   // 3 x 64x64
  const int tid = threadIdx.x;
  const int lane = tid & 63;
  const int wbase = (tid & 192) * 8;
  const int m0 = blockIdx.y * 128, n0 = blockIdx.x * 64;
  const int wm = ((tid >> 7) & 1) * 64;
  const int wn = ((tid >> 6) & 1) * 32;
  const int arow = tid >> 3, aslot = tid & 7;

  f32x4 accq[4][2], acck[4][2], accv[4][2];
#pragma unroll
  for (int i = 0; i < 4; ++i)
#pragma unroll
    for (int j = 0; j < 2; ++j) {
#pragma unroll
      for (int r = 0; r < 4; ++r) { accq[i][j][r] = 0.f; acck[i][j][r] = 0.f; accv[i][j][r] = 0.f; }
    }

  auto stage = [&](int t, int buf) {
#pragma unroll
    for (int q = 0; q < 4; ++q) {
      int row = q * 32 + arow;
      int sl = aslot ^ (row & 7);
      gld_lds16(A + (size_t)(m0 + row) * 512 + t * 64 + sl * 8,
                &As[buf][q * 2048 + wbase]);
    }
    const u16* bp[3] = {Bq, Bk, Bv};
#pragma unroll
    for (int w = 0; w < 3; ++w)
#pragma unroll
      for (int q = 0; q < 2; ++q) {
        int row = q * 32 + arow;
        int sl = aslot ^ (row & 7);
        gld_lds16(bp[w] + (size_t)(n0 + row) * 512 + t * 64 + sl * 8,
                  &Ws[w][buf][q * 2048 + wbase]);
      }
  };

  stage(0, 0);
  __syncthreads();
  int cur = 0;
#pragma unroll 1
  for (int t = 0; t < 8; ++t) {
    if (t < 7) stage(t + 1, cur ^ 1);
    const u16* la = As[cur];
    bf16x8 af[4][2];
#pragma unroll
    for (int mf = 0; mf < 4; ++mf)
#pragma unroll
      for (int ks = 0; ks < 2; ++ks) {
        int row = wm + mf * 16 + (lane & 15);
        int s = ks * 4 + (lane >> 4);
        af[mf][ks] = *(const bf16x8*)(la + row * 64 + ((s ^ (row & 7)) << 3));
      }
    __builtin_amdgcn_s_setprio(1);
#pragma unroll
    for (int ks = 0; ks < 2; ++ks)
#pragma unroll
      for (int nf = 0; nf < 2; ++nf) {
        int row = wn + nf * 16 + (lane & 15);
        int s = ks * 4 + (lane >> 4);
        int boff = row * 64 + ((s ^ (row & 7)) << 3);
        bf16x8 bq8 = *(const bf16x8*)(Ws[0][cur] + boff);
        bf16x8 bk8 = *(const bf16x8*)(Ws[1][cur] + boff);
        bf16x8 bv8 = *(const bf16x8*)(Ws[2][cur] + boff);
#pragma unroll
        for (int mf = 0; mf < 4; ++mf) {
          accq[mf][nf] = __builtin_amdgcn_mfma_f32_16x16x32_bf16(af[mf][ks], bq8, accq[mf][nf], 0, 0, 0);
          acck[mf][nf] = __builtin_amdgcn_mfma_f32_16x16x32_bf16(af[mf][ks], bk8, acck[mf][nf], 0, 0, 0);
          accv[mf][nf] = __builtin_amdgcn_mfma_f32_16x16x32_bf16(af[mf][ks], bv8, accv[mf][nf], 0, 0, 0);
        }
      }
    __builtin_amdgcn_s_setprio(0);
    __syncthreads();
    cur ^= 1;
  }

  // epilogue
  int h[2], d[2]; float bqv[2], bkv[2], bvv[2];
#pragma unroll
  for (int nf = 0; nf < 2; ++nf) {
    int col = n0 + wn + nf * 16 + (lane & 15);
    h[nf] = col >> 6; d[nf] = col & 63;
    bqv[nf] = bq[col]; bkv[nf] = bk[col]; bvv[nf] = bv[col];
  }
#pragma unroll
  for (int mf = 0; mf < 4; ++mf) {
    int mb = m0 + wm + mf * 16 + ((lane >> 4) << 2);
    int b = mb >> 12, t = (mb >> 10) & 3, row32 = (mb >> 5) & 31, col32 = mb & 31;
    int zi = row32 >> 4, hirow = row32 & 15, zj = col32 >> 4, wj = col32 & 15;
    int gb = b * 32 + (zi * 2 + zj) * 8;
    int l0 = t * 256 + hirow * 16 + wj;
#pragma unroll
    for (int nf = 0; nf < 2; ++nf) {
      size_t qkbase = ((size_t)(gb + h[nf]) * 1024 + l0) * 64 + d[nf];
#pragma unroll
      for (int r = 0; r < 4; ++r) {
        qw[qkbase + (size_t)r * 64] = f2b(accq[mf][nf][r] + bqv[nf]);
        kw[qkbase + (size_t)r * 64] = f2b(acck[mf][nf][r] + bkv[nf]);
      }
      ushort4 pv;
      pv.x = f2b(accv[mf][nf][0] + bvv[nf]);
      pv.y = f2b(accv[mf][nf][1] + bvv[nf]);
      pv.z = f2b(accv[mf][nf][2] + bvv[nf]);
      pv.w = f2b(accv[mf][nf][3] + bvv[nf]);
      *(ushort4*)(vt + ((size_t)(gb + h[nf]) * 64 + d[nf]) * 1024 + l0) = pv;
    }
  }
}

// ---------------------------------------------------------------------------
// Attention R4: 32x32 MFMA swapped QK^T, in-register softmax.
// K and V^T chunks double-buffered in LDS via global_load_lds (shared by the
// block's 4 waves). Grid flattened to 512 with XCD swizzle so all 8 q-tiles
// of a group (and 8 whole groups) live on one XCD -> K/V L2-resident.
// ---------------------------------------------------------------------------
__global__ __launch_bounds__(256)
void attn32(const u16* __restrict__ qw, const u16* __restrict__ kw,
            const u16* __restrict__ vt, u16* __restrict__ attb)
{
  __shared__ u16 Kl[2][4096];   // [64 key][64 d], rows 128B, slot^=(row&7)
  __shared__ u16 Vl[2][4096];   // [64 d][64 key], rows 128B, slot^=(row&7)

  const int tid = threadIdx.x, lane = tid & 63, wid = tid >> 6;
  const int hi = lane >> 5, ln = lane & 31;
  const int n = blockIdx.x;
  const int work = (n & 7) * 64 + (n >> 3);   // XCD-contiguous remap (512%8==0)
  const int g = work >> 3, qt = work & 7;
  const int b = g >> 5, z = (g >> 3) & 3, h = g & 7, zi = z >> 1, zj = z & 1;
  const u16* qg = qw + (size_t)g * 65536;
  const u16* kg = kw + (size_t)g * 65536;
  const u16* vg = vt + (size_t)g * 65536;
  const int q0 = qt * 128 + wid * 32;
  const float SC2 = 0.125f * 1.44269504089f;   // scale * log2(e)
  const float THR2 = 11.5415603f;              // 8 * log2(e)

  // staging geometry: wave w stages rows [16w,16w+16) of K and of V^T
  const int t8 = lane >> 3, s8 = lane & 7;
  const int gsl = s8 ^ t8;                     // pre-swizzled source slot

  auto stageKV = [&](int c, int buf) {
#pragma unroll
    for (int p = 0; p < 2; ++p) {
      int row = wid * 16 + p * 8 + t8;         // key row (K) / d row (V^T)
      gld_lds16(kg + (size_t)(c * 64 + row) * 64 + gsl * 8,
                Kl[buf] + wid * 1024 + p * 512);
      gld_lds16(vg + (size_t)row * 1024 + c * 64 + gsl * 8,
                Vl[buf] + wid * 1024 + p * 512);
    }
  };

  // Q fragments straight from global (one-time)
  bf16x8 qf[4];
#pragma unroll
  for (int ks = 0; ks < 4; ++ks)
    qf[ks] = *(const bf16x8*)(qg + (size_t)(q0 + ln) * 64 + ks * 16 + hi * 8);

  f32x16 o[2];
#pragma unroll
  for (int nf = 0; nf < 2; ++nf)
#pragma unroll
    for (int r = 0; r < 16; ++r) o[nf][r] = 0.f;
  float m2run = -INFINITY, lrun = 0.f;

  stageKV(0, 0);
  __syncthreads();
  int cur = 0;

#pragma unroll 1
  for (int c = 0; c < 16; ++c) {
    if (c < 15) stageKV(c + 1, cur ^ 1);

    // ---- K fragments from LDS ----
    bf16x8 kk[2][4];
#pragma unroll
    for (int kb = 0; kb < 2; ++kb)
#pragma unroll
      for (int ks = 0; ks < 4; ++ks) {
        int row = kb * 32 + ln;
        int sl = (ks * 2 + hi) ^ (ln & 7);
        kk[kb][ks] = *(const bf16x8*)(Kl[cur] + row * 64 + sl * 8);
      }

    // ---- S^T = K Q^T ----
    f32x16 st[2];
#pragma unroll
    for (int kb = 0; kb < 2; ++kb)
#pragma unroll
      for (int r = 0; r < 16; ++r) st[kb][r] = 0.f;
    __builtin_amdgcn_s_setprio(1);
#pragma unroll
    for (int ks = 0; ks < 4; ++ks) {
      st[0] = __builtin_amdgcn_mfma_f32_32x32x16_bf16(kk[0][ks], qf[ks], st[0], 0, 0, 0);
      st[1] = __builtin_amdgcn_mfma_f32_32x32x16_bf16(kk[1][ks], qf[ks], st[1], 0, 0, 0);
    }
    __builtin_amdgcn_s_setprio(0);

    // ---- online softmax (lane owns q=ln; 32 key scores in regs) ----
    float mx = fmaxf(st[0][0], fmaxf(st[0][1], st[0][2]));
#pragma unroll
    for (int r = 3; r < 16; r += 2) mx = fmaxf(mx, fmaxf(st[0][r], st[0][r + 1]));
    mx = fmaxf(mx, st[0][15]);
#pragma unroll
    for (int r = 0; r < 16; r += 2) mx = fmaxf(mx, fmaxf(st[1][r], st[1][r + 1]));
    mx = fmaxf(mx, __shfl_xor(mx, 32));
    float mx2 = mx * SC2;
    if (!__all(mx2 <= m2run + THR2)) {
      float mn = fmaxf(m2run, mx2);
      float scl = exp2f(m2run - mn);
      lrun *= scl;
      m2run = mn;
#pragma unroll
      for (int r = 0; r < 16; ++r) {
        float sb = __shfl(scl, (r & 3) + 8 * (r >> 2) + 4 * hi);
        o[0][r] *= sb; o[1][r] *= sb;
      }
    }
    float nm = -m2run;
    float rs = 0.f;
#pragma unroll
    for (int kb = 0; kb < 2; ++kb)
#pragma unroll
      for (int r = 0; r < 16; ++r) {
        float p = exp2f(fmaf(st[kb][r], SC2, nm));
        st[kb][r] = p;
        rs += p;
      }
    rs += __shfl_xor(rs, 32);
    lrun += rs;

    // ---- P (C-layout) -> A-frag via cvt_pk + permlane32_swap ----
    u32 W[2][4][2];
#pragma unroll
    for (int kb = 0; kb < 2; ++kb)
#pragma unroll
      for (int j = 0; j < 4; ++j)
#pragma unroll
        for (int u = 0; u < 2; ++u) {
          u32 w;
          asm("v_cvt_pk_bf16_f32 %0, %1, %2"
              : "=v"(w) : "v"(st[kb][4 * j + 2 * u]), "v"(st[kb][4 * j + 2 * u + 1]));
          W[kb][j][u] = w;
        }
    __builtin_amdgcn_s_setprio(1);
#pragma unroll
    for (int ks = 0; ks < 4; ++ks) {
      const int kb = ks >> 1, sl2 = ks & 1;
      u32 a0 = W[kb][2 * sl2][0], b0 = W[kb][2 * sl2 + 1][0];
      u32 a1 = W[kb][2 * sl2][1], b1 = W[kb][2 * sl2 + 1][1];
      asm volatile("v_permlane32_swap_b32 %0, %1" : "+v"(a0), "+v"(b0));
      asm volatile("v_permlane32_swap_b32 %0, %1" : "+v"(a1), "+v"(b1));
      union { u32 u[4]; bf16x8 v; } pu;
      pu.u[0] = a0; pu.u[1] = a1; pu.u[2] = b0; pu.u[3] = b1;
#pragma unroll
      for (int nf = 0; nf < 2; ++nf) {
        int drow = nf * 32 + ln;
        int vsl = (ks * 2 + hi) ^ (ln & 7);
        bf16x8 vf = *(const bf16x8*)(Vl[cur] + drow * 64 + vsl * 8);
        o[nf] = __builtin_amdgcn_mfma_f32_32x32x16_bf16(pu.v, vf, o[nf], 0, 0, 0);
      }
    }
    __builtin_amdgcn_s_setprio(0);

    __syncthreads();   // drains vmcnt (next chunk staged) + guards buf reuse
    cur ^= 1;
  }

  // ---- epilogue: normalize, store bf16 to x-layout ----
  const int rowbase = b * 4096 + zi * 512 + zj * 16;
  const int colbase = h * 64;
#pragma unroll
  for (int r = 0; r < 16; ++r) {
    int qr = (r & 3) + 8 * (r >> 2) + 4 * hi;
    float lv = __shfl(lrun, qr);
    float iv = 1.f / lv;
    int l = q0 + qr;
    int row = rowbase + ((l >> 8) << 10) + (((l >> 4) & 15) << 5) + (l & 15);
    size_t off = (size_t)row * 512 + colbase + ln;
    attb[off] = f2b(o[0][r] * iv);
    attb[off + 32] = f2b(o[1][r] * iv);
  }
}

// ---------------------------------------------------------------------------
// Output GEMM: out[m][n] = att[m][:] . Wo[n][:] + bo, f32 out
// ---------------------------------------------------------------------------
__global__ __launch_bounds__(256, 2)
void gemm_o(const u16* __restrict__ A, const u16* __restrict__ B,
            const float* __restrict__ bias, float* __restrict__ Cout)
{
  __shared__ u16 lds[2][12288];
  const int tid = threadIdx.x;
  const int lane = tid & 63;
  const int wbase = (tid & 192) * 8;
  const int m0 = blockIdx.y * 128, n0 = blockIdx.x * 64;
  const int wm = ((tid >> 7) & 1) * 64;
  const int wn = ((tid >> 6) & 1) * 32;
  const int arow = tid >> 3, aslot = tid & 7;

  f32x4 acc[4][2];
#pragma unroll
  for (int i = 0; i < 4; ++i)
#pragma unroll
    for (int j = 0; j < 2; ++j)
#pragma unroll
      for (int r = 0; r < 4; ++r) acc[i][j][r] = 0.f;

  auto stage = [&](int t, int buf) {
#pragma unroll
    for (int q = 0; q < 4; ++q) {
      int row = q * 32 + arow;
      int sl = aslot ^ (row & 7);
      gld_lds16(A + (size_t)(m0 + row) * 512 + t * 64 + sl * 8,
                &lds[buf][q * 2048 + wbase]);
    }
#pragma unroll
    for (int q = 0; q < 2; ++q) {
      int row = q * 32 + arow;
      int sl = aslot ^ (row & 7);
      gld_lds16(B + (size_t)(n0 + row) * 512 + t * 64 + sl * 8,
                &lds[buf][8192 + q * 2048 + wbase]);
    }
  };

  stage(0, 0);
  __syncthreads();
  int cur = 0;
#pragma unroll 1
  for (int t = 0; t < 8; ++t) {
    if (t < 7) stage(t + 1, cur ^ 1);
    const u16* la = lds[cur];
    const u16* lb = lds[cur] + 8192;
    bf16x8 af[4][2];
#pragma unroll
    for (int mf = 0; mf < 4; ++mf)
#pragma unroll
      for (int ks = 0; ks < 2; ++ks) {
        int row = wm + mf * 16 + (lane & 15);
        int s = ks * 4 + (lane >> 4);
        af[mf][ks] = *(const bf16x8*)(la + row * 64 + ((s ^ (row & 7)) << 3));
      }
    __builtin_amdgcn_s_setprio(1);
#pragma unroll
    for (int ks = 0; ks < 2; ++ks)
#pragma unroll
      for (int nf = 0; nf < 2; ++nf) {
        int row = wn + nf * 16 + (lane & 15);
        int s = ks * 4 + (lane >> 4);
        bf16x8 bfr = *(const bf16x8*)(lb + row * 64 + ((s ^ (row & 7)) << 3));
#pragma unroll
        for (int mf = 0; mf < 4; ++mf)
          acc[mf][nf] = __builtin_amdgcn_mfma_f32_16x16x32_bf16(af[mf][ks], bfr, acc[mf][nf], 0, 0, 0);
      }
    __builtin_amdgcn_s_setprio(0);
    __syncthreads();
    cur ^= 1;
  }

#pragma unroll
  for (int mf = 0; mf < 4; ++mf)
#pragma unroll
    for (int nf = 0; nf < 2; ++nf) {
      int row = m0 + wm + mf * 16 + ((lane >> 4) << 2);
      int col = n0 + wn + nf * 16 + (lane & 15);
      float bi = bias[col];
#pragma unroll
      for (int r = 0; r < 4; ++r)
        Cout[(size_t)(row + r) * 512 + col] = acc[mf][nf][r] + bi;
    }
}

// ---------------------------------------------------------------------------
extern "C" void kernel_launch(void* const* d_in, const int* in_sizes, int n_in,
                              void* d_out, int out_size, void* d_ws, size_t ws_size,
                              hipStream_t stream) {
  const float* x  = (const float*)d_in[0];
  const float* Wq = (const float*)d_in[2];
  const float* bq = (const float*)d_in[3];
  const float* Wk = (const float*)d_in[4];
  const float* bk = (const float*)d_in[5];
  const float* Wv = (const float*)d_in[6];
  const float* bv = (const float*)d_in[7];
  const float* Wo = (const float*)d_in[8];
  const float* bo = (const float*)d_in[9];

  u16* xb   = (u16*)d_ws;            // 8192*512
  u16* wqb  = xb + 4194304;
  u16* wkb  = wqb + 262144;
  u16* wvb  = wkb + 262144;
  u16* wob  = wvb + 262144;
  u16* qwb  = wob + 262144;          // [64][1024][64]
  u16* kwb  = qwb + 4194304;
  u16* vtb  = kwb + 4194304;         // [64][64][1024]
  u16* attb = vtb + 4194304;         // x-layout

  prep_cvt<<<5120, 256, 0, stream>>>(x, Wq, Wk, Wv, Wo, xb, wqb, wkb, wvb, wob);
  gemm_qkv<<<dim3(8, 64), 256, 0, stream>>>(xb, wqb, wkb, wvb, bq, bk, bv, qwb, kwb, vtb);
  attn32<<<512, 256, 0, stream>>>(qwb, kwb, vtb, attb);
  gemm_o<<<dim3(8, 64), 256, 0, stream>>>(attb, wob, bo, (float*)d_out);
}